// Round 14
// baseline (1386.359 us; speedup 1.0000x reference)
//
#include <hip/hip_runtime.h>
#include <hip/hip_cooperative_groups.h>

namespace cg = cooperative_groups;

#define NN 50000
#define NE 800000
#define NH 64
#define NG 500
#define NPAD 50176   // 196*256
#define NBKT 782     // ceil(NN/64) 64-node buckets
#define CAP 1536     // padded bucket capacity (max bucket deg ~1130; 4.5+ sigma margin)
#define NCHUNK ((NE + 8191) / 8192)

// fp32 -> bf16 round-to-nearest-even
__device__ __forceinline__ unsigned short f2bf(float f) {
  unsigned x = __float_as_uint(f);
  unsigned r = ((x >> 16) & 1u) + 0x7fffu;
  return (unsigned short)((x + r) >> 16);
}
__device__ __forceinline__ float bf2f(unsigned short u) {
  return __uint_as_float(((unsigned)u) << 16);
}

// ---------------- single persistent cooperative kernel ----------------
// Phases (separated by threadfence + grid.sync):
//   A: zero bcur      B: bin edges into padded 64-node buckets (line-dense writes)
//   C: bucket sort -> CSR (rowst/rowen/dinv) + gptr from sorted batch
//   D: encoder X0 = [x|pos] @ encW + encb
//   5x { gemm tiles (dual GEMM, bf16 hW out, fp32 agg) ; paired-row gather }
//   E: pool
// W mats staged to LDS once, resident across all 5 layers. 48 KB LDS -> 3 blocks/CU.

__global__ __launch_bounds__(256, 3) void k_all(
    const float* __restrict__ x, const float* __restrict__ pos,
    const int* __restrict__ src, const int* __restrict__ dst, const int* __restrict__ batch,
    const float* __restrict__ encW, const float* __restrict__ encb,
    const float* __restrict__ Wc, const float* __restrict__ cb,
    const float* __restrict__ Wr, const float* __restrict__ rb,
    const float* __restrict__ decW, const float* __restrict__ decb,
    float* __restrict__ out,
    float* __restrict__ dinv, int* __restrict__ rowst, int* __restrict__ rowen,
    int* __restrict__ bcur, int* __restrict__ gptr, float* __restrict__ Xo,
    int* __restrict__ colp, int* __restrict__ cols,
    unsigned short* __restrict__ hWbf, unsigned short* __restrict__ gsum,
    float* __restrict__ bufA, float* __restrict__ bufB) {
  cg::grid_group grid = cg::this_grid();
  __shared__ float smem[12288];  // 48 KB, aliased per phase
  int t = threadIdx.x;
  int nblk = gridDim.x;
  int gtid = blockIdx.x * 256 + t;
  int gsz = nblk * 256;

  // ---- phase A: zero bucket cursors ----
  for (int i = gtid; i < 1024; i += gsz) bcur[i] = 0;
  __threadfence();
  grid.sync();

  // ---- phase B: bin (LDS hist -> bulk reserve -> rank-addressed writes) ----
  {
    int* ihist = (int*)smem;
    int* igbase = ihist + NBKT;
    for (int chunk = blockIdx.x; chunk < NCHUNK; chunk += nblk) {
      for (int b = t; b < NBKT; b += 256) ihist[b] = 0;
      __syncthreads();
      int e0 = chunk * 8192;
#pragma unroll
      for (int i = 0; i < 32; i++) {
        int e = e0 + i * 256 + t;
        if (e < NE) atomicAdd(&ihist[dst[e] >> 6], 1);
      }
      __syncthreads();
      for (int b = t; b < NBKT; b += 256) {
        int c = ihist[b];
        igbase[b] = c ? atomicAdd(&bcur[b], c) : 0;
        ihist[b] = 0;  // reuse as rank counter
      }
      __syncthreads();
#pragma unroll
      for (int i = 0; i < 32; i++) {
        int e = e0 + i * 256 + t;
        if (e < NE) {
          int s = src[e], d = dst[e];
          int b = d >> 6;
          int r = atomicAdd(&ihist[b], 1);
          colp[b * CAP + igbase[b] + r] = (s << 6) | (d & 63);
        }
      }
      __syncthreads();
    }
  }
  __threadfence();
  grid.sync();

  // ---- phase C: bucket-local sort to CSR + dinv/rowst/rowen; then gptr ----
  {
    int* chist = (int*)smem;
    int* cexcl = chist + 64;
    for (int bb = blockIdx.x; bb < NBKT; bb += nblk) {
      int base = bb * CAP;
      int cnt = bcur[bb];
      if (t < 64) chist[t] = 0;
      __syncthreads();
      for (int e = t; e < cnt; e += 256) atomicAdd(&chist[colp[base + e] & 63], 1);
      __syncthreads();
      if (t == 0) {
        int run = 0;
#pragma unroll
        for (int i = 0; i < 64; i++) { cexcl[i] = run; run += chist[i]; }
        cexcl[64] = run;
      }
      __syncthreads();
      if (t < 64) {
        int n = bb * 64 + t;
        rowst[n] = base + cexcl[t];
        rowen[n] = base + cexcl[t + 1];
        if (n < NN) dinv[n] = rsqrtf((float)(chist[t] + 1));  // +1 self-loop
        chist[t] = 0;  // reuse as cursor
      }
      __syncthreads();
      for (int e = t; e < cnt; e += 256) {
        int w = colp[base + e];
        int d = w & 63;
        int r = atomicAdd(&chist[d], 1);
        cols[base + cexcl[d] + r] = w >> 6;
      }
      __syncthreads();
    }
    // gptr: graph segment pointers from sorted batch (no LDS, no barriers)
    for (int i = gtid; i < NN; i += gsz) {
      int bi = batch[i];
      int bp = (i > 0) ? batch[i - 1] : -1;
      for (int g = bp + 1; g <= bi; g++) gptr[g] = i;
      if (i == NN - 1) {
        for (int g = bi + 1; g <= NG; g++) gptr[g] = NN;
      }
    }
  }
  __threadfence();
  grid.sync();

  // ---- phase D: encoder ----
  {
    float* Ws = smem;         // 1024
    float* bs = smem + 1024;  // 64
    for (int i = t; i < 1024; i += 256) Ws[i] = encW[i];
    if (t < 64) bs[t] = encb[t];
    __syncthreads();
    int wid = t >> 6, h = t & 63;
    for (int g0 = blockIdx.x; g0 < NN / 4; g0 += nblk) {
      int n = g0 * 4 + wid;
      float acc = bs[h];
#pragma unroll
      for (int f = 0; f < 14; f++) acc += x[n * 14 + f] * Ws[f * 64 + h];
      acc += pos[n * 2 + 0] * Ws[14 * 64 + h];
      acc += pos[n * 2 + 1] * Ws[15 * 64 + h];
      bufA[n * 64 + h] = acc;
    }
    __syncthreads();  // smem about to be restaged
  }
  __threadfence();
  grid.sync();

  // ---- stage Wc/Wr into LDS ONCE for all 5 layers ----
  float* Xs = smem;          // 4096
  float* Wcs = smem + 4096;  // 4096
  float* Wrs = smem + 8192;  // 4096
#pragma unroll
  for (int j = 0; j < 4; j++) {
    ((float4*)Wcs)[t + j * 256] = ((const float4*)Wc)[t + j * 256];
    ((float4*)Wrs)[t + j * 256] = ((const float4*)Wr)[t + j * 256];
  }
  __syncthreads();

  int lane = t & 63;
  int wid = t >> 6;
  int h2 = lane & 31;  // gather: h-pair
  int p = lane >> 5;   // gather: pair member
  float dW0 = decW[h2 * 2], dW1 = decW[h2 * 2 + 1];
  // gemm thread mapping
  int hg = (t & 15) << 2;
  int ng = t >> 4;
  int nb_ = ng << 2;
  int swz = (ng & 7) << 2;
  float4 cbv = *(const float4*)(cb + hg);
  float4 rbv = *(const float4*)(rb + hg);

  float* aggIn = bufA;
  float* aggOut = bufB;

  for (int l = 0; l < 5; l++) {
    int mode = (l > 0) ? 1 : 0;
    int last = (l == 4) ? 1 : 0;

    // ---- gemm phase ----
    for (int bb = blockIdx.x; bb < NBKT; bb += nblk) {
      int n0 = bb * 64;
#pragma unroll
      for (int i = 0; i < 4; i++) {
        int idx = t + i * 256;
        int n = idx >> 4;
        int kg = (idx & 15) << 2;
        float4 v = make_float4(0.f, 0.f, 0.f, 0.f);
        int gn = n0 + n;
        if (gn < NN) {
          v = *(const float4*)(aggIn + gn * 64 + kg);
          if (mode) {
            ushort4 g4 = *(const ushort4*)(gsum + gn * 64 + kg);
            float dvn = dinv[gn];
            v.x = fmaxf(v.x + dvn * bf2f(g4.x), 0.f);
            v.y = fmaxf(v.y + dvn * bf2f(g4.y), 0.f);
            v.z = fmaxf(v.z + dvn * bf2f(g4.z), 0.f);
            v.w = fmaxf(v.w + dvn * bf2f(g4.w), 0.f);
          }
        }
        int sw = ((n >> 2) & 7) << 2;
        *(float4*)(Xs + n * 64 + (kg ^ sw)) = v;
      }
      __syncthreads();

      float aC[4][4] = {};
      float aR[4][4] = {};
#pragma unroll 4
      for (int k = 0; k < 64; k++) {
        float4 wc = *(const float4*)(Wcs + k * 64 + hg);
        float4 wr = *(const float4*)(Wrs + k * 64 + hg);
        int kk = k ^ swz;
#pragma unroll
        for (int i = 0; i < 4; i++) {
          float xv = Xs[(nb_ + i) * 64 + kk];
          aC[i][0] += xv * wc.x; aC[i][1] += xv * wc.y; aC[i][2] += xv * wc.z; aC[i][3] += xv * wc.w;
          aR[i][0] += xv * wr.x; aR[i][1] += xv * wr.y; aR[i][2] += xv * wr.z; aR[i][3] += xv * wr.w;
        }
      }

#pragma unroll
      for (int i = 0; i < 4; i++) {
        int n = n0 + nb_ + i;
        if (n < NN) {
          float dv = dinv[n];
          float4 hv;
          hv.x = dv * aC[i][0]; hv.y = dv * aC[i][1]; hv.z = dv * aC[i][2]; hv.w = dv * aC[i][3];
          ushort4 hb;
          hb.x = f2bf(hv.x); hb.y = f2bf(hv.y); hb.z = f2bf(hv.z); hb.w = f2bf(hv.w);
          *(ushort4*)(hWbf + (size_t)n * 64 + hg) = hb;
          float4 av;
          av.x = aR[i][0] + rbv.x + cbv.x + dv * hv.x;
          av.y = aR[i][1] + rbv.y + cbv.y + dv * hv.y;
          av.z = aR[i][2] + rbv.z + cbv.z + dv * hv.z;
          av.w = aR[i][3] + rbv.w + cbv.w + dv * hv.w;
          *(float4*)(aggOut + n * 64 + hg) = av;
        }
      }
      __syncthreads();  // Xs restaged next iteration
    }
    __threadfence();
    grid.sync();

    // ---- gather phase (paired rows: 2 edges per load instruction) ----
    for (int g0 = blockIdx.x; g0 < NN / 4; g0 += nblk) {
      int n = g0 * 4 + wid;  // wave-uniform
      int st = rowst[n];
      int en = rowen[n];
      int deg = en - st;
      float a0 = 0.f, a1 = 0.f;
      for (int base = 0; base < deg; base += 64) {
        int cnt = deg - base;
        if (cnt > 64) cnt = 64;
        int li = lane < cnt ? lane : cnt - 1;
        int colv = cols[st + base + li];
        for (int j = 0; j < cnt; j += 16) {
          int e0 = j + 0 + p, e1 = j + 2 + p, e2 = j + 4 + p, e3 = j + 6 + p;
          int e4 = j + 8 + p, e5 = j + 10 + p, e6 = j + 12 + p, e7 = j + 14 + p;
          int s0 = __shfl(colv, e0 < cnt ? e0 : j, 64);
          int s1 = __shfl(colv, e1 < cnt ? e1 : j, 64);
          int s2 = __shfl(colv, e2 < cnt ? e2 : j, 64);
          int s3 = __shfl(colv, e3 < cnt ? e3 : j, 64);
          int s4 = __shfl(colv, e4 < cnt ? e4 : j, 64);
          int s5 = __shfl(colv, e5 < cnt ? e5 : j, 64);
          int s6 = __shfl(colv, e6 < cnt ? e6 : j, 64);
          int s7 = __shfl(colv, e7 < cnt ? e7 : j, 64);
          unsigned u0 = *(const unsigned*)(hWbf + (size_t)s0 * 64 + h2 * 2);
          unsigned u1 = *(const unsigned*)(hWbf + (size_t)s1 * 64 + h2 * 2);
          unsigned u2 = *(const unsigned*)(hWbf + (size_t)s2 * 64 + h2 * 2);
          unsigned u3 = *(const unsigned*)(hWbf + (size_t)s3 * 64 + h2 * 2);
          unsigned u4 = *(const unsigned*)(hWbf + (size_t)s4 * 64 + h2 * 2);
          unsigned u5 = *(const unsigned*)(hWbf + (size_t)s5 * 64 + h2 * 2);
          unsigned u6 = *(const unsigned*)(hWbf + (size_t)s6 * 64 + h2 * 2);
          unsigned u7 = *(const unsigned*)(hWbf + (size_t)s7 * 64 + h2 * 2);
          a0 += (e0 < cnt) ? bf2f((unsigned short)(u0 & 0xffff)) : 0.f;
          a1 += (e0 < cnt) ? bf2f((unsigned short)(u0 >> 16)) : 0.f;
          a0 += (e1 < cnt) ? bf2f((unsigned short)(u1 & 0xffff)) : 0.f;
          a1 += (e1 < cnt) ? bf2f((unsigned short)(u1 >> 16)) : 0.f;
          a0 += (e2 < cnt) ? bf2f((unsigned short)(u2 & 0xffff)) : 0.f;
          a1 += (e2 < cnt) ? bf2f((unsigned short)(u2 >> 16)) : 0.f;
          a0 += (e3 < cnt) ? bf2f((unsigned short)(u3 & 0xffff)) : 0.f;
          a1 += (e3 < cnt) ? bf2f((unsigned short)(u3 >> 16)) : 0.f;
          a0 += (e4 < cnt) ? bf2f((unsigned short)(u4 & 0xffff)) : 0.f;
          a1 += (e4 < cnt) ? bf2f((unsigned short)(u4 >> 16)) : 0.f;
          a0 += (e5 < cnt) ? bf2f((unsigned short)(u5 & 0xffff)) : 0.f;
          a1 += (e5 < cnt) ? bf2f((unsigned short)(u5 >> 16)) : 0.f;
          a0 += (e6 < cnt) ? bf2f((unsigned short)(u6 & 0xffff)) : 0.f;
          a1 += (e6 < cnt) ? bf2f((unsigned short)(u6 >> 16)) : 0.f;
          a0 += (e7 < cnt) ? bf2f((unsigned short)(u7 & 0xffff)) : 0.f;
          a1 += (e7 < cnt) ? bf2f((unsigned short)(u7 >> 16)) : 0.f;
        }
      }
      a0 += __shfl_down(a0, 32, 64);
      a1 += __shfl_down(a1, 32, 64);
      if (!last) {
        if (lane < 32) {
          unsigned outw = (unsigned)f2bf(a0) | ((unsigned)f2bf(a1) << 16);
          *(unsigned*)(gsum + (size_t)n * 64 + h2 * 2) = outw;
        }
      } else {
        float dv = dinv[n];
        float2 ag = *(const float2*)(aggOut + (size_t)n * 64 + h2 * 2);
        float xf0 = ag.x + dv * a0;
        float xf1 = ag.y + dv * a1;
        float v = fmaxf(xf0, 0.f) * dW0 + fmaxf(xf1, 0.f) * dW1;
        v = (lane < 32) ? v : 0.f;
#pragma unroll
        for (int off = 32; off > 0; off >>= 1) v += __shfl_down(v, off, 64);
        if (lane == 0) Xo[n] = v;
      }
    }
    __threadfence();
    grid.sync();

    float* tmp = aggIn; aggIn = aggOut; aggOut = tmp;
  }

  // ---- pool ----
  {
    float* part = smem;  // W mats dead now
    float db = decb[0];
    for (int g = blockIdx.x; g < NG; g += nblk) {
      int st = gptr[g], en = gptr[g + 1];
      float v = 0.f;
      for (int i = st + t; i < en; i += 256) v += Xo[i];
#pragma unroll
      for (int off = 32; off > 0; off >>= 1) v += __shfl_down(v, off, 64);
      __syncthreads();  // part reuse across loop iterations
      if ((t & 63) == 0) part[t >> 6] = v;
      __syncthreads();
      if (t == 0) out[g] = part[0] + part[1] + part[2] + part[3] + (float)(en - st) * db;
    }
  }
}

// ---------------- launch ----------------

extern "C" void kernel_launch(void* const* d_in, const int* in_sizes, int n_in,
                              void* d_out, int out_size, void* d_ws, size_t ws_size,
                              hipStream_t stream) {
  (void)in_sizes; (void)n_in; (void)out_size; (void)ws_size;
  const float* x     = (const float*)d_in[0];
  const float* pos   = (const float*)d_in[1];
  const int*   ei    = (const int*)d_in[2];
  const int*   batch = (const int*)d_in[3];
  const float* encW  = (const float*)d_in[4];
  const float* encb  = (const float*)d_in[5];
  const float* convW = (const float*)d_in[6];
  const float* convb = (const float*)d_in[7];
  const float* resW  = (const float*)d_in[8];
  const float* resb  = (const float*)d_in[9];
  const float* decW  = (const float*)d_in[10];
  const float* decb  = (const float*)d_in[11];
  float* out = (float*)d_out;

  const int* src = ei;       // edge_index[0]
  const int* dst = ei + NE;  // edge_index[1]

  // workspace layout (4-byte elems)
  float*          ws     = (float*)d_ws;
  float*          dinv   = ws;                          // [NPAD]
  int*            rowst  = (int*)(ws + NPAD);           // [NPAD]
  int*            rowen  = (int*)(ws + 2 * NPAD);       // [NPAD]
  int*            bcur   = (int*)(ws + 3 * NPAD);       // [1024]
  int*            gptr   = bcur + 1024;                 // [NG+1]
  float*          Xo     = (float*)(gptr + 512);        // [NPAD]
  int*            colp   = (int*)(Xo + NPAD);           // [NBKT*CAP]
  int*            cols   = colp + NBKT * CAP;           // [NBKT*CAP]
  unsigned short* hWbf   = (unsigned short*)(cols + NBKT * CAP);  // [NPAD*64] bf16
  unsigned short* gsum   = hWbf + (size_t)NPAD * 64;              // [NPAD*64] bf16
  float*          bufA   = (float*)(gsum + (size_t)NPAD * 64);    // [NN*NH]
  float*          bufB   = bufA + NN * NH;

  // co-resident grid: 48 KB LDS -> 3 blocks/CU -> 768; clamp by occupancy query
  int nb = 0;
  if (hipOccupancyMaxActiveBlocksPerMultiprocessor(&nb, k_all, 256, 0) != hipSuccess || nb < 1) nb = 1;
  int gridn = nb * 256;
  if (gridn > 768) gridn = 768;

  void* args[] = {(void*)&x, (void*)&pos, (void*)&src, (void*)&dst, (void*)&batch,
                  (void*)&encW, (void*)&encb, (void*)&convW, (void*)&convb,
                  (void*)&resW, (void*)&resb, (void*)&decW, (void*)&decb, (void*)&out,
                  (void*)&dinv, (void*)&rowst, (void*)&rowen, (void*)&bcur, (void*)&gptr,
                  (void*)&Xo, (void*)&colp, (void*)&cols, (void*)&hWbf, (void*)&gsum,
                  (void*)&bufA, (void*)&bufB};
  hipLaunchCooperativeKernel((void*)k_all, dim3(gridn), dim3(256), args, 0, stream);
}

// Round 15
// 329.382 us; speedup vs baseline: 4.2090x; 4.2090x over previous
//
#include <hip/hip_runtime.h>

#define NN 50000
#define NE 800000
#define NH 64
#define NG 500
#define NPAD 50176   // 196*256
#define NBKT 782     // ceil(NN/64) 64-node buckets
#define CAP 1536     // padded bucket capacity (max bucket deg ~1130; 4.5+ sigma margin)

// fp32 -> bf16 round-to-nearest-even
__device__ __forceinline__ unsigned short f2bf(float f) {
  unsigned x = __float_as_uint(f);
  unsigned r = ((x >> 16) & 1u) + 0x7fffu;
  return (unsigned short)((x + r) >> 16);
}
__device__ __forceinline__ float bf2f(unsigned short u) {
  return __uint_as_float(((unsigned)u) << 16);
}

// ---------------- binning into padded buckets: colp[b*CAP + r] ----------------

__global__ __launch_bounds__(256) void k_bin(const int* __restrict__ src, const int* __restrict__ dst,
                                             int* __restrict__ bcur, int* __restrict__ colp) {
  __shared__ int hist[NBKT];
  __shared__ int gbase[NBKT];
  int t = threadIdx.x;
  for (int b = t; b < NBKT; b += 256) hist[b] = 0;
  __syncthreads();
  int e0 = blockIdx.x * 8192;
#pragma unroll
  for (int i = 0; i < 32; i++) {
    int e = e0 + i * 256 + t;
    if (e < NE) atomicAdd(&hist[dst[e] >> 6], 1);
  }
  __syncthreads();
  for (int b = t; b < NBKT; b += 256) {
    int c = hist[b];
    gbase[b] = c ? atomicAdd(&bcur[b], c) : 0;
    hist[b] = 0;  // reuse as rank counter
  }
  __syncthreads();
#pragma unroll
  for (int i = 0; i < 32; i++) {
    int e = e0 + i * 256 + t;
    if (e < NE) {
      int s = src[e], d = dst[e];
      int b = d >> 6;
      int r = atomicAdd(&hist[b], 1);
      colp[b * CAP + gbase[b] + r] = (s << 6) | (d & 63);
    }
  }
}

// ---------------- bucket-local sort to padded CSR + dinv/rowst/rowen (+ gptr folded) ----------------

__global__ __launch_bounds__(256) void k_csr(const int* __restrict__ bcur, const int* __restrict__ colp,
                                             int* __restrict__ cols, float* __restrict__ dinv,
                                             int* __restrict__ rowst, int* __restrict__ rowen,
                                             const int* __restrict__ batch, int* __restrict__ gptr) {
  __shared__ int hist[64];
  __shared__ int excl[65];
  int t = threadIdx.x;
  int b = blockIdx.x;

  // folded gptr: graph segment pointers from sorted batch (independent work)
  int tid = b * 256 + t;
  if (tid < NN) {
    int bi = batch[tid];
    int bp = (tid > 0) ? batch[tid - 1] : -1;
    for (int g = bp + 1; g <= bi; g++) gptr[g] = tid;
    if (tid == NN - 1) {
      for (int g = bi + 1; g <= NG; g++) gptr[g] = NN;
    }
  }

  int base = b * CAP;
  int cnt = bcur[b];
  if (t < 64) hist[t] = 0;
  __syncthreads();
  for (int e = t; e < cnt; e += 256) atomicAdd(&hist[colp[base + e] & 63], 1);
  __syncthreads();
  if (t == 0) {
    int run = 0;
#pragma unroll
    for (int i = 0; i < 64; i++) { excl[i] = run; run += hist[i]; }
    excl[64] = run;
  }
  __syncthreads();
  if (t < 64) {
    int n = b * 64 + t;
    rowst[n] = base + excl[t];
    rowen[n] = base + excl[t + 1];
    if (n < NN) dinv[n] = rsqrtf((float)(hist[t] + 1));  // +1 self-loop
    hist[t] = 0;  // reuse as cursor
  }
  __syncthreads();
  for (int e = t; e < cnt; e += 256) {
    int w = colp[base + e];
    int d = w & 63;
    int r = atomicAdd(&hist[d], 1);
    cols[base + excl[d] + r] = w >> 6;
  }
}

// ---------------- encoder: X0 = [x|pos] @ enc_W + enc_b ----------------

__global__ __launch_bounds__(256) void k_encoder(const float* __restrict__ x, const float* __restrict__ pos,
                                                 const float* __restrict__ W, const float* __restrict__ b,
                                                 float* __restrict__ X0) {
  __shared__ float Ws[16 * 64];
  __shared__ float bs[64];
  int t = threadIdx.x;
  for (int i = t; i < 1024; i += 256) Ws[i] = W[i];
  if (t < 64) bs[t] = b[t];
  __syncthreads();
  int n = blockIdx.x * 4 + (t >> 6);
  int h = t & 63;
  if (n >= NN) return;
  float acc = bs[h];
#pragma unroll
  for (int f = 0; f < 14; f++) acc += x[n * 14 + f] * Ws[f * 64 + h];
  acc += pos[n * 2 + 0] * Ws[14 * 64 + h];
  acc += pos[n * 2 + 1] * Ws[15 * 64 + h];
  X0[n * 64 + h] = acc;
}

// ---------------- fused dual GEMM + epilogue (64-node tile, 48 KB LDS -> 3 blocks/CU) ----------------
// mode 0: X = Xin (encoder output). mode 1: X = relu(Xin + dinv[n]*bf2f(gsum[n])).
// hWbf = bf16( dinv[n] * (X @ conv_W) )   (gather sums these)
// agg  = X @ res_W + res_b + conv_b + dinv[n]*hWs[n]   (self-loop in fp32)

__global__ __launch_bounds__(256) void k_gemm_dual(const float* __restrict__ Xin,
                                                   const unsigned short* __restrict__ gsum,
                                                   const float* __restrict__ Wc, const float* __restrict__ Wr,
                                                   const float* __restrict__ cb, const float* __restrict__ rb,
                                                   const float* __restrict__ dinv,
                                                   unsigned short* __restrict__ hWbf, float* __restrict__ agg,
                                                   int mode) {
  __shared__ float Xs[64 * 64];
  __shared__ float Wcs[64 * 64];
  __shared__ float Wrs[64 * 64];
  int t = threadIdx.x;
#pragma unroll
  for (int j = 0; j < 4; j++) {
    ((float4*)Wcs)[t + j * 256] = ((const float4*)Wc)[t + j * 256];
    ((float4*)Wrs)[t + j * 256] = ((const float4*)Wr)[t + j * 256];
  }
  int n0 = blockIdx.x * 64;
#pragma unroll
  for (int i = 0; i < 4; i++) {
    int idx = t + i * 256;        // float4 index in 64x64 tile (1024 total)
    int n = idx >> 4;             // 16 float4 per row
    int kg = (idx & 15) << 2;
    float4 v = make_float4(0.f, 0.f, 0.f, 0.f);
    int gn = n0 + n;
    if (gn < NN) {
      v = *(const float4*)(Xin + gn * 64 + kg);
      if (mode) {
        ushort4 g = *(const ushort4*)(gsum + gn * 64 + kg);
        float dvn = dinv[gn];
        v.x = fmaxf(v.x + dvn * bf2f(g.x), 0.f);
        v.y = fmaxf(v.y + dvn * bf2f(g.y), 0.f);
        v.z = fmaxf(v.z + dvn * bf2f(g.z), 0.f);
        v.w = fmaxf(v.w + dvn * bf2f(g.w), 0.f);
      }
    }
    int sw = ((n >> 2) & 7) << 2;  // float4-preserving bank swizzle
    *(float4*)(Xs + n * 64 + (kg ^ sw)) = v;
  }
  __syncthreads();

  int hg = (t & 15) << 2;   // h0 (4 consecutive h)
  int ng = t >> 4;          // node group (16 groups x 4 nodes)
  int nb = ng << 2;
  int swz = (ng & 7) << 2;  // rows nb..nb+3 share row>>2 == ng

  float aC[4][4] = {};
  float aR[4][4] = {};
#pragma unroll 4
  for (int k = 0; k < 64; k++) {
    float4 wc = *(const float4*)(Wcs + k * 64 + hg);
    float4 wr = *(const float4*)(Wrs + k * 64 + hg);
    int kk = k ^ swz;
#pragma unroll
    for (int i = 0; i < 4; i++) {
      float xv = Xs[(nb + i) * 64 + kk];
      aC[i][0] += xv * wc.x; aC[i][1] += xv * wc.y; aC[i][2] += xv * wc.z; aC[i][3] += xv * wc.w;
      aR[i][0] += xv * wr.x; aR[i][1] += xv * wr.y; aR[i][2] += xv * wr.z; aR[i][3] += xv * wr.w;
    }
  }

  float4 cbv = *(const float4*)(cb + hg);
  float4 rbv = *(const float4*)(rb + hg);
#pragma unroll
  for (int i = 0; i < 4; i++) {
    int n = n0 + nb + i;
    if (n < NN) {
      float dv = dinv[n];
      float4 hv;
      hv.x = dv * aC[i][0]; hv.y = dv * aC[i][1]; hv.z = dv * aC[i][2]; hv.w = dv * aC[i][3];
      ushort4 hb;
      hb.x = f2bf(hv.x); hb.y = f2bf(hv.y); hb.z = f2bf(hv.z); hb.w = f2bf(hv.w);
      *(ushort4*)(hWbf + (size_t)n * 64 + hg) = hb;
      float4 av;
      av.x = aR[i][0] + rbv.x + cbv.x + dv * hv.x;
      av.y = aR[i][1] + rbv.y + cbv.y + dv * hv.y;
      av.z = aR[i][2] + rbv.z + cbv.z + dv * hv.z;
      av.w = aR[i][3] + rbv.w + cbv.w + dv * hv.w;
      *(float4*)(agg + n * 64 + hg) = av;
    }
  }
}

// ---------------- CSR gather, QUAD rows: 4 edges per load instruction ----------------
// One 64-lane wave per dst node. Lane = (p = lane>>4 in [0,4), h4 = lane&15): handles
// h = 4*h4..4*h4+3 of edge-slot quad-member p. One dwordx2 load = 64 lanes x 8 B =
// 512 B = FOUR bf16 rows -> 4 load instructions per 16 edges (R13 pairing: 8).
// Outstanding cache LINES per batch unchanged (16) — only instruction count halves.
// End: combine the 4 p-groups (2 shuffles); lanes 0..15 write one coalesced 128 B
// gsum line. Last layer reads agg once and fuses decode.

__global__ __launch_bounds__(256) void k_gather(const int* __restrict__ rowst, const int* __restrict__ rowen,
                                                const int* __restrict__ cols,
                                                const unsigned short* __restrict__ hWbf,
                                                unsigned short* __restrict__ gsum,
                                                const float* __restrict__ agg, const float* __restrict__ dinv,
                                                const float* __restrict__ decW, float* __restrict__ Xo,
                                                int last) {
  int lane = threadIdx.x & 63;
  int h4 = lane & 15;   // h quad: h = 4*h4 .. 4*h4+3
  int p = lane >> 4;    // quad member (edge slot within group of 4)
  int n = __builtin_amdgcn_readfirstlane(blockIdx.x * 4 + (threadIdx.x >> 6));
  int st = rowst[n];
  int en = rowen[n];
  int deg = en - st;
  float a0 = 0.f, a1 = 0.f, a2 = 0.f, a3 = 0.f;
  for (int base = 0; base < deg; base += 64) {
    int cnt = deg - base;
    if (cnt > 64) cnt = 64;
    int li = lane < cnt ? lane : cnt - 1;
    int colv = cols[st + base + li];  // one coalesced load of up to 64 indices
    for (int j = 0; j < cnt; j += 16) {
      int e0 = j + p, e1 = j + 4 + p, e2 = j + 8 + p, e3 = j + 12 + p;
      int s0 = __shfl(colv, e0 < cnt ? e0 : j, 64);
      int s1 = __shfl(colv, e1 < cnt ? e1 : j, 64);
      int s2 = __shfl(colv, e2 < cnt ? e2 : j, 64);
      int s3 = __shfl(colv, e3 < cnt ? e3 : j, 64);
      uint2 u0 = *(const uint2*)(hWbf + (size_t)s0 * 64 + h4 * 4);
      uint2 u1 = *(const uint2*)(hWbf + (size_t)s1 * 64 + h4 * 4);
      uint2 u2 = *(const uint2*)(hWbf + (size_t)s2 * 64 + h4 * 4);
      uint2 u3 = *(const uint2*)(hWbf + (size_t)s3 * 64 + h4 * 4);
      if (e0 < cnt) {
        a0 += bf2f((unsigned short)(u0.x & 0xffff));
        a1 += bf2f((unsigned short)(u0.x >> 16));
        a2 += bf2f((unsigned short)(u0.y & 0xffff));
        a3 += bf2f((unsigned short)(u0.y >> 16));
      }
      if (e1 < cnt) {
        a0 += bf2f((unsigned short)(u1.x & 0xffff));
        a1 += bf2f((unsigned short)(u1.x >> 16));
        a2 += bf2f((unsigned short)(u1.y & 0xffff));
        a3 += bf2f((unsigned short)(u1.y >> 16));
      }
      if (e2 < cnt) {
        a0 += bf2f((unsigned short)(u2.x & 0xffff));
        a1 += bf2f((unsigned short)(u2.x >> 16));
        a2 += bf2f((unsigned short)(u2.y & 0xffff));
        a3 += bf2f((unsigned short)(u2.y >> 16));
      }
      if (e3 < cnt) {
        a0 += bf2f((unsigned short)(u3.x & 0xffff));
        a1 += bf2f((unsigned short)(u3.x >> 16));
        a2 += bf2f((unsigned short)(u3.y & 0xffff));
        a3 += bf2f((unsigned short)(u3.y >> 16));
      }
    }
  }
  // combine the 4 quad-members: lanes 0..15 get full sums for their h quad
  a0 += __shfl_down(a0, 32, 64); a0 += __shfl_down(a0, 16, 64);
  a1 += __shfl_down(a1, 32, 64); a1 += __shfl_down(a1, 16, 64);
  a2 += __shfl_down(a2, 32, 64); a2 += __shfl_down(a2, 16, 64);
  a3 += __shfl_down(a3, 32, 64); a3 += __shfl_down(a3, 16, 64);
  if (!last) {
    if (lane < 16) {
      ushort4 hb;
      hb.x = f2bf(a0); hb.y = f2bf(a1); hb.z = f2bf(a2); hb.w = f2bf(a3);
      *(ushort4*)(gsum + (size_t)n * 64 + h4 * 4) = hb;  // 16 lanes x 8 B = 128 B line
    }
  } else {
    float dv = dinv[n];
    float4 ag = *(const float4*)(agg + (size_t)n * 64 + h4 * 4);   // valid addr all lanes
    float4 dw = *(const float4*)(decW + h4 * 4);
    float v = fmaxf(ag.x + dv * a0, 0.f) * dw.x + fmaxf(ag.y + dv * a1, 0.f) * dw.y +
              fmaxf(ag.z + dv * a2, 0.f) * dw.z + fmaxf(ag.w + dv * a3, 0.f) * dw.w;
    v = (lane < 16) ? v : 0.f;  // other lanes hold stale partials
#pragma unroll
    for (int off = 32; off > 0; off >>= 1) v += __shfl_down(v, off, 64);
    if (lane == 0) Xo[n] = v;
  }
}

// ---------------- graph pooling: out[g] = sum Xo[gptr[g]:gptr[g+1]] + cnt*decb ----------------

__global__ __launch_bounds__(256) void k_pool(const float* __restrict__ Xo, const int* __restrict__ gptr,
                                              const float* __restrict__ decb, float* __restrict__ out) {
  __shared__ float part[4];
  int g = blockIdx.x;
  int t = threadIdx.x;
  int st = gptr[g], en = gptr[g + 1];
  float v = 0.f;
  for (int i = st + t; i < en; i += 256) v += Xo[i];
#pragma unroll
  for (int off = 32; off > 0; off >>= 1) v += __shfl_down(v, off, 64);
  if ((t & 63) == 0) part[t >> 6] = v;
  __syncthreads();
  if (t == 0) out[g] = part[0] + part[1] + part[2] + part[3] + (float)(en - st) * decb[0];
}

// ---------------- launch ----------------

extern "C" void kernel_launch(void* const* d_in, const int* in_sizes, int n_in,
                              void* d_out, int out_size, void* d_ws, size_t ws_size,
                              hipStream_t stream) {
  (void)in_sizes; (void)n_in; (void)out_size; (void)ws_size;
  const float* x     = (const float*)d_in[0];
  const float* pos   = (const float*)d_in[1];
  const int*   ei    = (const int*)d_in[2];
  const int*   batch = (const int*)d_in[3];
  const float* encW  = (const float*)d_in[4];
  const float* encb  = (const float*)d_in[5];
  const float* convW = (const float*)d_in[6];
  const float* convb = (const float*)d_in[7];
  const float* resW  = (const float*)d_in[8];
  const float* resb  = (const float*)d_in[9];
  const float* decW  = (const float*)d_in[10];
  const float* decb  = (const float*)d_in[11];
  float* out = (float*)d_out;

  const int* src = ei;       // edge_index[0]
  const int* dst = ei + NE;  // edge_index[1]

  // workspace layout (4-byte elems)
  float*          ws     = (float*)d_ws;
  float*          dinv   = ws;                          // [NPAD]
  int*            rowst  = (int*)(ws + NPAD);           // [NPAD]
  int*            rowen  = (int*)(ws + 2 * NPAD);       // [NPAD]
  int*            bcur   = (int*)(ws + 3 * NPAD);       // [1024]
  int*            gptr   = bcur + 1024;                 // [NG+1]
  float*          Xo     = (float*)(gptr + 512);        // [NPAD]
  int*            colp   = (int*)(Xo + NPAD);           // [NBKT*CAP] packed (src<<6)|dstLow
  int*            cols   = colp + NBKT * CAP;           // [NBKT*CAP] sorted src
  unsigned short* hWbf   = (unsigned short*)(cols + NBKT * CAP);        // [NPAD*64] bf16
  unsigned short* gsum   = hWbf + (size_t)NPAD * 64;                    // [NPAD*64] bf16
  float*          bufA   = (float*)(gsum + (size_t)NPAD * 64);          // [NN*NH]
  float*          bufB   = bufA + NN * NH;

  hipMemsetAsync(bcur, 0, 1024 * sizeof(int), stream);

  k_bin<<<(NE + 8191) / 8192, 256, 0, stream>>>(src, dst, bcur, colp);
  k_csr<<<NBKT, 256, 0, stream>>>(bcur, colp, cols, dinv, rowst, rowen, batch, gptr);

  k_encoder<<<(NN + 3) / 4, 256, 0, stream>>>(x, pos, encW, encb, bufA);

  float* aggIn = bufA;   // X0 for l=0; thereafter agg_{l-1}
  float* aggOut = bufB;
  for (int l = 0; l < 5; l++) {
    int last = (l == 4) ? 1 : 0;
    k_gemm_dual<<<NBKT, 256, 0, stream>>>(aggIn, gsum, convW, resW, convb, resb, dinv,
                                          hWbf, aggOut, l > 0 ? 1 : 0);
    k_gather<<<NN / 4, 256, 0, stream>>>(rowst, rowen, cols, hWbf, gsum,
                                         aggOut, dinv, decW, Xo, last);
    float* tmp = aggIn; aggIn = aggOut; aggOut = tmp;
  }
  k_pool<<<NG, 256, 0, stream>>>(Xo, gptr, decb, out);
}